// Round 1
// baseline (29.855 us; speedup 1.0000x reference)
//
#include <hip/hip_runtime.h>
#include <math.h>

#define EPS 1e-7f

// Kernel 1: per-block partial sums of (1 - ciou) over the M box pairs.
__global__ __launch_bounds__(256) void ciou_partial_kernel(
    const float4* __restrict__ preds,
    const float4* __restrict__ targets,
    float* __restrict__ partials,
    int m)
{
    int tid = blockIdx.x * blockDim.x + threadIdx.x;
    int stride = gridDim.x * blockDim.x;

    float acc = 0.0f;
    for (int i = tid; i < m; i += stride) {
        float4 p = preds[i];    // x1,y1,w1,h1  (16B contiguous per lane)
        float4 t = targets[i];  // x2,y2,w2,h2

        float x1 = p.x, y1 = p.y, w1 = p.z, h1 = p.w;
        float x2 = t.x, y2 = t.y, w2 = t.z, h2 = t.w;

        float w1h = 0.5f * w1, h1h = 0.5f * h1;
        float w2h = 0.5f * w2, h2h = 0.5f * h2;

        float b1x1 = x1 - w1h, b1x2 = x1 + w1h;
        float b1y1 = y1 - h1h, b1y2 = y1 + h1h;
        float b2x1 = x2 - w2h, b2x2 = x2 + w2h;
        float b2y1 = y2 - h2h, b2y2 = y2 + h2h;

        float iw = fmaxf(fminf(b1x2, b2x2) - fmaxf(b1x1, b2x1), 0.0f);
        float ih = fmaxf(fminf(b1y2, b2y2) - fmaxf(b1y1, b2y1), 0.0f);
        float inter = iw * ih;
        float uni = w1 * h1 + w2 * h2 - inter + EPS;
        float iou = inter / uni;

        float cw = fmaxf(b1x2, b2x2) - fminf(b1x1, b2x1);
        float ch = fmaxf(b1y2, b2y2) - fminf(b1y1, b2y1);
        float c2 = cw * cw + ch * ch + EPS;

        // ((b2x1+b2x2-b1x1-b1x2)^2 + (b2y1+b2y2-b1y1-b1y2)^2)/4
        //   == (x2-x1)^2 + (y2-y1)^2  (up to fp rounding)
        float dx = x2 - x1, dy = y2 - y1;
        float rho2 = dx * dx + dy * dy;

        const float c4pi2 = 4.0f / (float)(M_PI * M_PI);
        float da = atanf(w2 / (h2 + EPS)) - atanf(w1 / (h1 + EPS));
        float v = c4pi2 * da * da;
        float alpha = v / (v - iou + (1.0f + EPS));

        float ciou = iou - (rho2 / c2 + v * alpha);
        acc += 1.0f - ciou;
    }

    // 64-lane wave reduction
    #pragma unroll
    for (int off = 32; off > 0; off >>= 1)
        acc += __shfl_down(acc, off, 64);

    __shared__ float wsum[4];
    int lane = threadIdx.x & 63;
    int wid  = threadIdx.x >> 6;
    if (lane == 0) wsum[wid] = acc;
    __syncthreads();
    if (threadIdx.x == 0)
        partials[blockIdx.x] = wsum[0] + wsum[1] + wsum[2] + wsum[3];
}

// Kernel 2: deterministic final reduce (single block, double accumulation).
__global__ __launch_bounds__(256) void ciou_final_kernel(
    const float* __restrict__ partials,
    int nblocks,
    float* __restrict__ out,
    float inv_m)
{
    double acc = 0.0;
    for (int i = threadIdx.x; i < nblocks; i += 256)
        acc += (double)partials[i];

    #pragma unroll
    for (int off = 32; off > 0; off >>= 1)
        acc += __shfl_down(acc, off, 64);

    __shared__ double wsum[4];
    int lane = threadIdx.x & 63;
    int wid  = threadIdx.x >> 6;
    if (lane == 0) wsum[wid] = acc;
    __syncthreads();
    if (threadIdx.x == 0)
        out[0] = (float)((wsum[0] + wsum[1] + wsum[2] + wsum[3]) * (double)inv_m);
}

extern "C" void kernel_launch(void* const* d_in, const int* in_sizes, int n_in,
                              void* d_out, int out_size, void* d_ws, size_t ws_size,
                              hipStream_t stream)
{
    const float4* preds   = (const float4*)d_in[0];
    const float4* targets = (const float4*)d_in[1];
    float* out = (float*)d_out;
    float* partials = (float*)d_ws;

    int m = in_sizes[0] / 4;  // in_sizes[0] is flat count (M*4)

    int nblocks = 2048;
    size_t max_part = ws_size / sizeof(float);
    if ((size_t)nblocks > max_part) nblocks = (int)max_part;
    if (nblocks < 1) nblocks = 1;

    ciou_partial_kernel<<<nblocks, 256, 0, stream>>>(preds, targets, partials, m);
    ciou_final_kernel<<<1, 256, 0, stream>>>(partials, nblocks, out, 1.0f / (float)m);
}